// Round 4
// baseline (269.948 us; speedup 1.0000x reference)
//
#include <hip/hip_runtime.h>

// ROIAlign3d: x=[2,256,16,64,64] f32, rois=[64,5] -> out=[64,256,16,7,7] f32.
// R4: rank-1 separable weights. For each bin, the 4-sample bilinear sum
// factorizes exactly: W16 = (sum_gy vy*ybilin) (x) (sum_gx vx*xbilin), so each
// output = sum_{k<4} wy[k] * dot(pix[row_k, c0..c0+3], wx4): 8 ds_read2 reads
// instead of 16 scalar reads, and a 49-entry table (read once per wave).
// P=8 planes/block -> 15.4 KB LDS -> 8 blocks/CU (100% occupancy target).

#define NBINS 49
#define P     8             // t-planes per block
#define MAXR  17            // rows staged per plane
#define BW    24            // box width (floats), covers c0max(18)+3, mult of 4
#define PSTR  (MAXR * BW)   // 408 floats per plane
#define NSTG  (P * MAXR * 6)  // 816 float4 stage slots

__global__ __launch_bounds__(256) void roialign3d_kernel(
    const float* __restrict__ x, const float* __restrict__ rois,
    float* __restrict__ out)
{
    constexpr int C = 256, T = 16, H = 64, W = 64;
    constexpr float SCALE = 0.0625f;
    constexpr int TOT = 2 * C * T * H * W;   // 33,554,432

    __shared__ float  s_box[P * PSTR];   // 13,056 B
    __shared__ float4 s_wx[NBINS];       //    784 B
    __shared__ float4 s_wy[NBINS];       //    784 B
    __shared__ int4   s_rb[NBINS];       //    784 B

    const int b   = blockIdx.x;
    const int c   = b & 255;
    const int tg  = (b >> 8) & 1;
    const int r   = b >> 9;
    const int tid = threadIdx.x;

    // ---- uniform roi params ----
    const float r1 = rois[r*5+1], r2 = rois[r*5+2];
    const float r3 = rois[r*5+3], r4 = rois[r*5+4];
    const int   bidx = (int)rois[r*5+0];

    const float sw_ = r1 * SCALE, sh_ = r2 * SCALE;
    const float ew_ = r3 * SCALE, eh_ = r4 * SCALE;
    const float bin_w = fmaxf(ew_ - sw_, 1.0f) * (1.0f / 7.0f);
    const float bin_h = fmaxf(eh_ - sh_, 1.0f) * (1.0f / 7.0f);

    const float ys_f = sh_ + 0.25f * bin_h;
    const float xs_f = sw_ + 0.25f * bin_w;
    const int y_lo  = (int)floorf(fminf(fmaxf(ys_f, 0.0f), 63.0f));
    const int x_lo  = (int)floorf(fminf(fmaxf(xs_f, 0.0f), 63.0f));
    const int x4_lo = x_lo & ~3;

    // ---- 49-entry rank-1 table ----
    if (tid < NBINS) {
        const int ph = tid / 7, pw = tid - ph * 7;

        float wyv[2][2]; int yi[2][2];
#pragma unroll
        for (int g = 0; g < 2; ++g) {
            const float ys = sh_ + ((float)ph + 0.25f + 0.5f * (float)g) * bin_h;
            const bool  v  = (ys >= -1.0f) && (ys <= 64.0f);
            const float yc = fminf(fmaxf(ys, 0.0f), 63.0f);
            const int   y0 = (int)floorf(yc);
            const float ly = yc - (float)y0;
            yi[g][0] = y0; yi[g][1] = min(y0 + 1, H - 1);
            const float m = v ? 0.25f : 0.0f;          // fold 1/(sr*sr)
            wyv[g][0] = (1.0f - ly) * m; wyv[g][1] = ly * m;
        }

        float wx4[4] = {0.f, 0.f, 0.f, 0.f};
        int c0 = 0;
#pragma unroll
        for (int g = 0; g < 2; ++g) {
            const float xs = sw_ + ((float)pw + 0.25f + 0.5f * (float)g) * bin_w;
            const bool  v  = (xs >= -1.0f) && (xs <= 64.0f);
            const float xc = fminf(fmaxf(xs, 0.0f), 63.0f);
            const int   x0 = (int)floorf(xc);
            const float lx = xc - (float)x0;
            const int   x1 = min(x0 + 1, W - 1);
            const float vm = v ? 1.0f : 0.0f;
            if (g == 0) c0 = x0;
            wx4[x0 - c0] += (1.0f - lx) * vm;   // x0-c0 in {0,1,2}
            wx4[x1 - c0] += lx * vm;            // x1-c0 in {0..3}
        }
        const int cb = c0 - x4_lo;              // 0..18

        s_wx[tid] = make_float4(wx4[0], wx4[1], wx4[2], wx4[3]);
        s_wy[tid] = make_float4(wyv[0][0], wyv[0][1], wyv[1][0], wyv[1][1]);
        s_rb[tid] = make_int4((yi[0][0] - y_lo) * BW + cb,
                              (yi[0][1] - y_lo) * BW + cb,
                              (yi[1][0] - y_lo) * BW + cb,
                              (yi[1][1] - y_lo) * BW + cb);
    }

    // ---- stage 8-plane box: 17 rows x 6 float4 each, contiguous LDS writes --
    {
        const int pbase = ((bidx * C + c) * T + tg * P) << 12;
        for (int i = tid; i < NSTG; i += 256) {       // 816 -> 4 rounds
            const int p    = i / 102;                 // 102 = 17*6
            const int rem  = i - p * 102;
            const int row  = rem / 6;
            const int col  = rem - row * 6;
            const int rowc = min(y_lo + row, H - 1);  // pad rows (weight 0)
            int sidx = pbase + (p << 12) + (rowc << 6) + x4_lo + (col << 2);
            sidx = min(sidx, TOT - 4);                // array-end guard
            *(float4*)&s_box[p * PSTR + row * BW + (col << 2)] =
                *(const float4*)(x + sidx);
        }
    }
    __syncthreads();

    // ---- Phase B: wave w -> planes {2w, 2w+1}; lane -> bin pp ----
    const int wv   = tid >> 6;
    const int lane = tid & 63;
    const int pp   = min(lane, NBINS - 1);
    const float4 wx = s_wx[pp];
    const float4 wy = s_wy[pp];
    const int4   rb = s_rb[pp];

    if (lane < NBINS) {
        const size_t obase = ((size_t)((r * C + c) * T + tg * P)) * NBINS;
#pragma unroll
        for (int q = 0; q < 2; ++q) {
            const int p = wv * 2 + q;
            const float* __restrict__ bx = &s_box[p * PSTR];
            const float* q0 = bx + rb.x;
            const float* q1 = bx + rb.y;
            const float* q2 = bx + rb.z;
            const float* q3 = bx + rb.w;
            const float d0 = wx.x*q0[0] + wx.y*q0[1] + wx.z*q0[2] + wx.w*q0[3];
            const float d1 = wx.x*q1[0] + wx.y*q1[1] + wx.z*q1[2] + wx.w*q1[3];
            const float d2 = wx.x*q2[0] + wx.y*q2[1] + wx.z*q2[2] + wx.w*q2[3];
            const float d3 = wx.x*q3[0] + wx.y*q3[1] + wx.z*q3[2] + wx.w*q3[3];
            out[obase + p * NBINS + pp] = wy.x*d0 + wy.y*d1 + wy.z*d2 + wy.w*d3;
        }
    }
}

extern "C" void kernel_launch(void* const* d_in, const int* in_sizes, int n_in,
                              void* d_out, int out_size, void* d_ws, size_t ws_size,
                              hipStream_t stream) {
    const float* x    = (const float*)d_in[0];
    const float* rois = (const float*)d_in[1];
    float* out = (float*)d_out;

    // 64 rois * 2 t-groups * 256 channels = 32768 blocks
    roialign3d_kernel<<<dim3(32768), dim3(256), 0, stream>>>(x, rois, out);
}

// Round 5
// 253.790 us; speedup vs baseline: 1.0637x; 1.0637x over previous
//
#include <hip/hip_runtime.h>
#include <stdint.h>

// ROIAlign3d: x=[2,256,16,64,64] f32, rois=[64,5] -> out=[64,256,16,7,7] f32.
// R5: invert the loop nest. Block = (batch, channel, t) stages its FULL 16KB
// plane into LDS once (global_load_lds, contiguous), then computes all 32
// rois-of-batch x 49 bins = 1568 outputs. Rank-1 separable weight tables
// (wx4/wy4 + absolute 4-row bases rb4 per (roi,bin)) are built ONCE by a tiny
// pre-kernel into d_ws and read from L2. x is fetched from HBM exactly once.
//
// d_ws layout: wx float4[3136] @0 | wy float4[3136] @50176 | rb int4[3136]
// @100352 | list int[2][64] @150528 | cnt int[2] @151040  (151048 B total)

#define NBINS 49
#define NROIS 64
#define NTAB  (NROIS * NBINS)   // 3136

__global__ __launch_bounds__(256) void build_table_kernel(
    const float* __restrict__ rois,
    float4* __restrict__ wx, float4* __restrict__ wy, int4* __restrict__ rb,
    int* __restrict__ list, int* __restrict__ cnt)
{
    const int gid = blockIdx.x * 256 + threadIdx.x;

    if (gid == 0) {   // batch -> roi lists (general: any batch assignment)
        int c0 = 0, c1 = 0;
        for (int r = 0; r < NROIS; ++r) {
            const int b = (int)rois[r * 5];
            if (b == 0) list[c0++] = r; else list[64 + c1++] = r;
        }
        cnt[0] = c0; cnt[1] = c1;
    }
    if (gid >= NTAB) return;

    constexpr int H = 64, W = 64;
    constexpr float SCALE = 0.0625f;
    const int r  = gid / NBINS;
    const int pp = gid - r * NBINS;
    const int ph = pp / 7, pw = pp - ph * 7;

    const float sw_ = rois[r*5+1] * SCALE, sh_ = rois[r*5+2] * SCALE;
    const float ew_ = rois[r*5+3] * SCALE, eh_ = rois[r*5+4] * SCALE;
    const float bin_w = fmaxf(ew_ - sw_, 1.0f) * (1.0f / 7.0f);
    const float bin_h = fmaxf(eh_ - sh_, 1.0f) * (1.0f / 7.0f);

    // y side: 2 samples -> 4 row weights (valid mask & 1/4 folded)
    float wyv[2][2]; int yi[2][2];
#pragma unroll
    for (int g = 0; g < 2; ++g) {
        const float ys = sh_ + ((float)ph + 0.25f + 0.5f * (float)g) * bin_h;
        const bool  v  = (ys >= -1.0f) && (ys <= 64.0f);
        const float yc = fminf(fmaxf(ys, 0.0f), 63.0f);
        const int   y0 = (int)floorf(yc);
        const float ly = yc - (float)y0;
        yi[g][0] = y0; yi[g][1] = min(y0 + 1, H - 1);
        const float m = v ? 0.25f : 0.0f;
        wyv[g][0] = (1.0f - ly) * m; wyv[g][1] = ly * m;
    }

    // x side: 2 samples scatter-added into 4 consecutive cols from c0
    float wx4[4] = {0.f, 0.f, 0.f, 0.f};
    int c0 = 0;
#pragma unroll
    for (int g = 0; g < 2; ++g) {
        const float xs = sw_ + ((float)pw + 0.25f + 0.5f * (float)g) * bin_w;
        const bool  v  = (xs >= -1.0f) && (xs <= 64.0f);
        const float xc = fminf(fmaxf(xs, 0.0f), 63.0f);
        const int   x0 = (int)floorf(xc);
        const float lx = xc - (float)x0;
        const int   x1 = min(x0 + 1, W - 1);
        const float vm = v ? 1.0f : 0.0f;
        if (g == 0) c0 = x0;
        wx4[x0 - c0] += (1.0f - lx) * vm;   // in {0,1,2}
        wx4[x1 - c0] += lx * vm;            // in {0..3}
    }

    wx[gid] = make_float4(wx4[0], wx4[1], wx4[2], wx4[3]);
    wy[gid] = make_float4(wyv[0][0], wyv[0][1], wyv[1][0], wyv[1][1]);
    rb[gid] = make_int4(yi[0][0] * W + c0, yi[0][1] * W + c0,
                        yi[1][0] * W + c0, yi[1][1] * W + c0);
}

__global__ __launch_bounds__(256) void roialign3d_main(
    const float* __restrict__ x,
    const float4* __restrict__ wx, const float4* __restrict__ wy,
    const int4* __restrict__ rb,
    const int* __restrict__ list, const int* __restrict__ cnt,
    float* __restrict__ out)
{
    __shared__ float s_plane[4096 + 8];   // +8 slack: reads at base+3 past col63

    const int blk = blockIdx.x;           // = (b*256 + c)*16 + t
    const int t   = blk & 15;
    const int c   = (blk >> 4) & 255;
    const int b   = blk >> 12;
    const int tid = threadIdx.x;

    if (tid < 8) s_plane[4096 + tid] = 0.0f;   // weight-0 cols read here

    // ---- stage full plane (16 KB) via direct-to-LDS, contiguous ----
    {
        const float* gbase = x + ((size_t)blk << 12);
        const int wv = tid >> 6, lane = tid & 63;
#pragma unroll
        for (int j = 0; j < 4; ++j) {
            const int seg = wv * 4 + j;                 // 16 x 1KB segments
            const float* g = gbase + seg * 256 + lane * 4;
            float* l = s_plane + seg * 256;             // wave-uniform base
            __builtin_amdgcn_global_load_lds(
                (const __attribute__((address_space(1))) void*)g,
                (__attribute__((address_space(3))) void*)l, 16, 0, 0);
        }
    }
    __syncthreads();

    // ---- 1568 outputs: (roi-slot, bin) pairs, tables from L2 ----
    const int npairs = cnt[b] * NBINS;
    const int* __restrict__ lst = list + b * 64;

    for (int idx = tid; idx < npairs; idx += 256) {
        const int slot = idx / NBINS;
        const int bin  = idx - slot * NBINS;
        const int r    = lst[slot];
        const int e    = r * NBINS + bin;

        const float4 vx = wx[e];
        const float4 vy = wy[e];
        const int4   ro = rb[e];

        const float* q0 = s_plane + ro.x;
        const float* q1 = s_plane + ro.y;
        const float* q2 = s_plane + ro.z;
        const float* q3 = s_plane + ro.w;
        const float d0 = vx.x*q0[0] + vx.y*q0[1] + vx.z*q0[2] + vx.w*q0[3];
        const float d1 = vx.x*q1[0] + vx.y*q1[1] + vx.z*q1[2] + vx.w*q1[3];
        const float d2 = vx.x*q2[0] + vx.y*q2[1] + vx.z*q2[2] + vx.w*q2[3];
        const float d3 = vx.x*q3[0] + vx.y*q3[1] + vx.z*q3[2] + vx.w*q3[3];

        out[((r * 256 + c) * 16 + t) * NBINS + bin] =
            vy.x*d0 + vy.y*d1 + vy.z*d2 + vy.w*d3;
    }
}

extern "C" void kernel_launch(void* const* d_in, const int* in_sizes, int n_in,
                              void* d_out, int out_size, void* d_ws, size_t ws_size,
                              hipStream_t stream) {
    const float* x    = (const float*)d_in[0];
    const float* rois = (const float*)d_in[1];
    float* out = (float*)d_out;

    char* ws = (char*)d_ws;
    float4* wx  = (float4*)(ws);
    float4* wy  = (float4*)(ws + 50176);
    int4*   rb  = (int4*)  (ws + 100352);
    int*    lst = (int*)   (ws + 150528);
    int*    cnt = (int*)   (ws + 151040);

    // 13 blocks cover 3136 table entries (+ thread 0 builds batch lists)
    build_table_kernel<<<dim3(13), dim3(256), 0, stream>>>(rois, wx, wy, rb, lst, cnt);

    // 2 batches * 256 channels * 16 t = 8192 blocks, one full plane each
    roialign3d_main<<<dim3(8192), dim3(256), 0, stream>>>(x, wx, wy, rb, lst, cnt, out);
}